// Round 1
// 83.560 us; speedup vs baseline: 1.0041x; 1.0041x over previous
//
#include <hip/hip_runtime.h>
#include <float.h>

#define POOL 7
#define FW 2048
#define FH 2048
#define CROP 96

// One block per box, 256 threads, NO LDS staging.
// Bins of an adaptive max-pool PARTITION the crop (<=1 row/col overlap), so
// staging the window in LDS buys no reuse -- it only cost us the serial
// DMA -> vmcnt(0)-drain -> compute -> drain -> DMA -> drain -> compute chain
// (two exposed cold-HBM round trips per block; the harness's 256MiB poison
// fill wipes L2/L3 every iteration, so reads ARE cold).
//
// New structure: lane pair (s=0,1) per (channel, bin) unit: 2ch x 49 bins x 2
// = 196 lanes. Each lane reads its bin's rows straight from global as 5
// float4 (80B window; adjacent bins' windows tile the row contiguously, so
// wave-level coalescing is fine). Columns masked by precomputed sel floats:
// fmaxf(m, fminf(v, sel)), sel = in-bin ? +FLT_MAX : -FLT_MAX.
// Row loop count K is BLOCK-UNIFORM (scalar branch, zero divergence); row
// index is clamped to er-1, which just re-reads an in-bin row -- idempotent
// under max, so no row masking at all. Loads are double-buffered (A/B) so
// each lane keeps ~10 loads in flight across iterations.
__global__ __launch_bounds__(256, 4) void roi_pool_fc_kernel(
    const float* __restrict__ feature,   // [2, 2048, 2048]
    const float* __restrict__ boxes,     // [N, 6]
    const int*   __restrict__ coords,    // [N, 4] (y1, x1, y2, x2)
    const float* __restrict__ fc_w,      // [4, 98]
    const float* __restrict__ fc_b,      // [4]
    float* __restrict__ out,             // [N, 6]
    int N)
{
    const int n = blockIdx.x;
    const int t = threadIdx.x;

    __shared__ float pooled[98];         // channel-major: c*49 + i*7 + j
    __shared__ float delta[4];

    const int4 cd = ((const int4*)coords)[n];   // uniform -> s_load
    const int y1 = cd.x;
    const int x1 = cd.y;
    const int h  = cd.z - y1;   // 7 <= h <= 95
    const int w  = cd.w - x1;   // 7 <= w <= 95

    const int x1a = x1 & ~3;    // 16B-aligned window start
    const int off = x1 - x1a;   // 0..3

    // FC weight/bias/box prefetch (latency hidden under pooling loads)
    float wpre[4] = {0.f, 0.f, 0.f, 0.f};
    float bias = 0.f;
    if (t < 128) {
        const int oo = t >> 5, lane = t & 31;
        const float* wrow = fc_w + oo * 98;
        #pragma unroll
        for (int kk = 0; kk < 4; ++kk) {
            const int idx = lane + 32 * kk;
            if (idx < 98) wpre[kk] = wrow[idx];
        }
        if (lane == 0) bias = fc_b[oo];
    }
    const float bx = (t < 6) ? boxes[n * 6 + t] : 0.f;

    // uniform row-pair trip count: max bin height <= ceil(h/7)+1
    const int K = (((h + 6) / 7) + 2) >> 1;     // 1..8, SGPR loop bound

    if (t < 196) {
        const int s = t & 1;        // row parity within bin
        const int u = t >> 1;       // 0..97 = c*49 + o
        const int c = u / 49;
        const int o = u - c * 49;   // bin index i*7+j
        const int i = o / 7;
        const int j = o % 7;

        const int sr  = (i * h) / POOL;
        const int er  = ((i + 1) * h + POOL - 1) / POOL;
        const int sc  = (j * w) / POOL + off;
        const int ec  = ((j + 1) * w + POOL - 1) / POOL + off;  // ec-sc <= 15
        const int sc4 = sc >> 2;                                // <= 21

        float sel[20];
        #pragma unroll
        for (int q = 0; q < 20; ++q) {
            const int b = sc4 * 4 + q;
            sel[q] = (b >= sc && b < ec) ? FLT_MAX : -FLT_MAX;
        }

        // 16B-aligned; max over-read is ~16B past row end -> spills into the
        // next image row (max row index read is y2-1 <= 2045, so in-bounds).
        const float* cbase = feature + (size_t)c * ((size_t)FH * FW)
                           + (size_t)y1 * FW + x1a + 4 * sc4;
        const int rb    = sr + s;
        const int ermax = er - 1;

        float m = -FLT_MAX;
        float4 A[5], B[5];

        auto loadrow = [&](float4* V, int kk) {
            int rr = rb + 2 * kk;
            rr = (rr < ermax) ? rr : ermax;     // clamp: re-read in-bin row
            const float4* rp = (const float4*)(cbase + (size_t)rr * FW);
            #pragma unroll
            for (int q = 0; q < 5; ++q) V[q] = rp[q];
        };
        auto acc5 = [&](const float4* V) {
            #pragma unroll
            for (int q = 0; q < 5; ++q) {
                m = fmaxf(m, fminf(V[q].x, sel[4 * q + 0]));
                m = fmaxf(m, fminf(V[q].y, sel[4 * q + 1]));
                m = fmaxf(m, fminf(V[q].z, sel[4 * q + 2]));
                m = fmaxf(m, fminf(V[q].w, sel[4 * q + 3]));
            }
        };

        // software-pipelined: issue next row-pair's 5 loads before consuming
        loadrow(A, 0);
        int k = 1;
        for (; k + 1 < K; k += 2) {
            loadrow(B, k);
            acc5(A);
            loadrow(A, k + 1);
            acc5(B);
        }
        if (k < K) { loadrow(B, k); acc5(A); acc5(B); }
        else       { acc5(A); }

        m = fmaxf(m, __shfl_xor(m, 1, 64));     // combine s=0/1 partials
        if (s == 0) pooled[u] = m;
    }
    __syncthreads();

    // ---- FC (98 -> 4), 32 lanes per output, prefetched weights
    if (t < 128) {
        const int lane = t & 31;
        float acc = 0.f;
        #pragma unroll
        for (int kk = 0; kk < 4; ++kk) {
            const int idx = lane + 32 * kk;
            acc = fmaf(idx < 98 ? pooled[idx] : 0.f, wpre[kk], acc);
        }
        #pragma unroll
        for (int mm = 16; mm; mm >>= 1)
            acc += __shfl_xor(acc, mm, 64);   // masks <32 stay in 32-lane group
        if (lane == 0) delta[t >> 5] = fmaxf(acc + bias, 0.f);
    }
    __syncthreads();

    if (t < 6)
        out[n * 6 + t] = bx + (t >= 2 ? delta[t - 2] : 0.f);
}

extern "C" void kernel_launch(void* const* d_in, const int* in_sizes, int n_in,
                              void* d_out, int out_size, void* d_ws, size_t ws_size,
                              hipStream_t stream) {
    const float* feature = (const float*)d_in[0];  // [1,2,2048,2048] fp32
    const float* boxes   = (const float*)d_in[1];  // [N,6] fp32
    const int*   coords  = (const int*)d_in[2];    // [N,4] int32
    const float* fc_w    = (const float*)d_in[3];  // [4,98] fp32
    const float* fc_b    = (const float*)d_in[4];  // [4] fp32
    float* out = (float*)d_out;                    // [N,6] fp32

    const int N = in_sizes[2] / 4;
    roi_pool_fc_kernel<<<N, 256, 0, stream>>>(feature, boxes, coords, fc_w, fc_b, out, N);
}